// Round 4
// baseline (1760.644 us; speedup 1.0000x reference)
//
#include <hip/hip_runtime.h>
#include <hip/hip_bf16.h>

typedef unsigned short u16;
typedef unsigned long long u64;
typedef __attribute__((ext_vector_type(8))) short short8;
typedef __attribute__((ext_vector_type(16))) float floatx16;

#define NB 32
#define NCI 256
#define NCO 256
#define NW 4096
#define NK 5

#define W3ROWB 80                      // 32 bf16 (64B) + 16B pad per co-row
#define W3TILE (256 * W3ROWB)          // 20480 B per (cb,tap) tile
#define W3_BYTES (40 * W3TILE)         // 819200

#define XROWB 80                       // LDS X row: 32 ci' bf16 (64B) + 16B pad
#define XROWS 264                      // w0-4 .. w0+259 (halo baked in)
#define XBUF (XROWS * XROWB)           // 21120 B

// ---------------- pre-kernel: W fp32 -> bf16, [cb,t][co][ci'] 80B rows ----------------

__global__ void wprep(const float* __restrict__ wgt, u16* __restrict__ W3) {
    int i = blockIdx.x * 256 + threadIdx.x;       // co*1280 + ci*5 + k
    if (i >= NCO * NCI * NK) return;
    int k  = i % NK;
    int ci = (i / NK) % NCI;
    int co = i / (NCI * NK);
    int cb = ci >> 5, cr = ci & 31;
    __hip_bfloat16 h = __float2bfloat16(wgt[i]);
    W3[((size_t)(cb * NK + k) * 256 + co) * 40 + cr] = *reinterpret_cast<u16*>(&h);
}

// ---------------- fused conv: fp32 x -> bf16 transpose-stage -> MFMA -> fp32 out ----------------
// grid 512 = 16 w-tiles x 32 batch; block 256 thr = 4 waves.
// block tile 256co x 256w; wave tile 64co x 256w; mfma_f32_32x32x16_bf16,
// mi=2, ni=8, ks=2. af from global W3 (L1/L2-hot); bf from LDS X (dbuf, 1 barrier/cb).

__device__ __forceinline__ u16 bf16bits(float f) {
    __hip_bfloat16 h = __float2bfloat16(f);
    return *reinterpret_cast<u16*>(&h);
}

__global__ __launch_bounds__(256, 2)
void conv_mfma(const float* __restrict__ x, const u16* __restrict__ W3,
               const float* __restrict__ bias, float* __restrict__ out) {
    __shared__ __align__(16) char xlds[2 * XBUF];   // 42240 B

    const int bid  = blockIdx.x;
    const int wt   = bid & 15;
    const int b    = bid >> 4;
    const int tid  = threadIdx.x;
    const int lane = tid & 63;
    const int wm   = tid >> 6;         // wave 0..3 -> co strip wm*64
    const int l31  = lane & 31;
    const int g    = lane >> 5;
    const int w0   = wt * 256;

    floatx16 acc[2][8];
#pragma unroll
    for (int mi = 0; mi < 2; ++mi)
#pragma unroll
        for (int ni = 0; ni < 8; ++ni)
#pragma unroll
            for (int r = 0; r < 16; ++r) acc[mi][ni][r] = 0.f;

    const float* xb = x + (size_t)b * NCI * NW;

    // halo task (threads 0..63): side 0 -> rows 0..3 (w0-4..w0-1), side 1 -> rows 260..263
    const int hside = tid >> 5;
    const int hr    = (tid >> 3) & 3;
    const int hcq   = tid & 7;
    const int hrow  = hside ? (260 + hr) : hr;
    const int hwg   = hside ? (w0 + 256 + hr) : (w0 - 4 + hr);
    const bool hvalid = (hwg >= 0) && (hwg < NW);

    // ---------- prologue: stage cb = 0 into buf 0 ----------
    {
        float v[8][4];
        float hv[4] = {0.f, 0.f, 0.f, 0.f};
#pragma unroll
        for (int it = 0; it < 8; ++it)
#pragma unroll
            for (int q = 0; q < 4; ++q)
                v[it][q] = xb[(size_t)(it * 4 + q) * NW + w0 + tid];
        if (tid < 64 && hvalid)
#pragma unroll
            for (int q = 0; q < 4; ++q)
                hv[q] = xb[(size_t)(hcq * 4 + q) * NW + hwg];

        char* dst = xlds;
#pragma unroll
        for (int it = 0; it < 8; ++it) {
            u64 p = (u64)bf16bits(v[it][0]) | ((u64)bf16bits(v[it][1]) << 16) |
                    ((u64)bf16bits(v[it][2]) << 32) | ((u64)bf16bits(v[it][3]) << 48);
            *(u64*)(dst + (4 + tid) * XROWB + it * 8) = p;
        }
        if (tid < 64) {
            u64 p = (u64)bf16bits(hv[0]) | ((u64)bf16bits(hv[1]) << 16) |
                    ((u64)bf16bits(hv[2]) << 32) | ((u64)bf16bits(hv[3]) << 48);
            *(u64*)(dst + hrow * XROWB + hcq * 8) = p;
        }
    }
    __syncthreads();

    // ---------- main loop over 8 ci-blocks ----------
    for (int cb = 0; cb < 8; ++cb) {
        const char* cur = xlds + (cb & 1) * XBUF;
        char* nxt       = xlds + ((cb + 1) & 1) * XBUF;
        const bool more = (cb < 7);

        // T14 issue-early: global loads for cb+1
        float v[8][4];
        float hv[4] = {0.f, 0.f, 0.f, 0.f};
        if (more) {
            const float* xcb = xb + (size_t)((cb + 1) * 32) * NW;
#pragma unroll
            for (int it = 0; it < 8; ++it)
#pragma unroll
                for (int q = 0; q < 4; ++q)
                    v[it][q] = xcb[(size_t)(it * 4 + q) * NW + w0 + tid];
            if (tid < 64 && hvalid)
#pragma unroll
                for (int q = 0; q < 4; ++q)
                    hv[q] = xcb[(size_t)(hcq * 4 + q) * NW + hwg];
        }

        // compute cb: 5 taps x 2 ks x (2 af-global + 8 bf-LDS + 16 MFMA)
#pragma unroll
        for (int t = 0; t < NK; ++t) {
            const char* wtile = (const char*)W3 + (size_t)(cb * NK + t) * W3TILE;
#pragma unroll
            for (int ks = 0; ks < 2; ++ks) {
                short8 af[2], bf[8];
#pragma unroll
                for (int mi = 0; mi < 2; ++mi)
                    af[mi] = *(const short8*)(wtile +
                             (wm * 64 + mi * 32 + l31) * W3ROWB + ks * 32 + g * 16);
#pragma unroll
                for (int ni = 0; ni < 8; ++ni)
                    bf[ni] = *(const short8*)(cur +
                             (ni * 32 + l31 + t + 2) * XROWB + ks * 32 + g * 16);
#pragma unroll
                for (int mi = 0; mi < 2; ++mi)
#pragma unroll
                    for (int ni = 0; ni < 8; ++ni)
                        acc[mi][ni] = __builtin_amdgcn_mfma_f32_32x32x16_bf16(
                            af[mi], bf[ni], acc[mi][ni], 0, 0, 0);
            }
        }

        // T14 write-late: pack + ds_write into the other buffer, then barrier
        if (more) {
#pragma unroll
            for (int it = 0; it < 8; ++it) {
                u64 p = (u64)bf16bits(v[it][0]) | ((u64)bf16bits(v[it][1]) << 16) |
                        ((u64)bf16bits(v[it][2]) << 32) | ((u64)bf16bits(v[it][3]) << 48);
                *(u64*)(nxt + (4 + tid) * XROWB + it * 8) = p;
            }
            if (tid < 64) {
                u64 p = (u64)bf16bits(hv[0]) | ((u64)bf16bits(hv[1]) << 16) |
                        ((u64)bf16bits(hv[2]) << 32) | ((u64)bf16bits(hv[3]) << 48);
                *(u64*)(nxt + hrow * XROWB + hcq * 8) = p;
            }
            __syncthreads();
        }
    }

    // ---------- epilogue: C/D col=lane&31, row=(r&3)+8*(r>>2)+4*(lane>>5) ----------
#pragma unroll
    for (int mi = 0; mi < 2; ++mi) {
#pragma unroll
        for (int r = 0; r < 16; ++r) {
            int crow = (r & 3) + 8 * (r >> 2) + 4 * g;
            int co   = wm * 64 + mi * 32 + crow;
            float bv = bias[co];
            float* orow = out + ((size_t)b * NCO + co) * NW + w0 + l31;
#pragma unroll
            for (int ni = 0; ni < 8; ++ni)
                orow[ni * 32] = acc[mi][ni][r] + bv;
        }
    }
}

// ---------------- fallback (ws too small): naive fp32 ----------------

__global__ void conv_naive(const float* __restrict__ x, const float* __restrict__ wgt,
                           const float* __restrict__ bias, float* __restrict__ out) {
    int w  = blockIdx.x * 256 + threadIdx.x;
    int co = blockIdx.y;
    int b  = blockIdx.z;
    float acc = bias[co];
    for (int ci = 0; ci < NCI; ci++) {
        const float* xr = x + ((size_t)b * NCI + ci) * NW;
        const float* wr = wgt + ((size_t)co * NCI + ci) * NK;
#pragma unroll
        for (int k = 0; k < NK; k++) {
            int wi = w + k - 2;
            if (wi >= 0 && wi < NW) acc += xr[wi] * wr[k];
        }
    }
    out[((size_t)b * NCO + co) * NW + w] = acc;
}

// ---------------- launch ----------------

extern "C" void kernel_launch(void* const* d_in, const int* in_sizes, int n_in,
                              void* d_out, int out_size, void* d_ws, size_t ws_size,
                              hipStream_t stream) {
    const float* x    = (const float*)d_in[0];
    const float* wgt  = (const float*)d_in[1];
    const float* bias = (const float*)d_in[2];
    float* out        = (float*)d_out;

    if (ws_size < (size_t)W3_BYTES) {
        conv_naive<<<dim3(NW / 256, NCO, NB), 256, 0, stream>>>(x, wgt, bias, out);
        return;
    }

    u16* W3 = (u16*)d_ws;
    wprep<<<(NCO * NCI * NK + 255) / 256, 256, 0, stream>>>(wgt, W3);
    conv_mfma<<<512, 256, 0, stream>>>(x, W3, bias, out);
}

// Round 5
// 108.052 us; speedup vs baseline: 16.2945x; 16.2945x over previous
//
#include <hip/hip_runtime.h>
#include <hip/hip_bf16.h>

typedef unsigned short u16;
typedef unsigned int u32;
typedef unsigned long long u64;
typedef __attribute__((ext_vector_type(8))) short short8;
typedef __attribute__((ext_vector_type(4))) float floatx4;

#define NB 32
#define NCI 256
#define NCO 256
#define NW 4096
#define NK 5

#define W3ROWB 80                      // 32 bf16 (64B) + 16B pad per co-row
#define W3TILE (256 * W3ROWB)          // 20480 B per (cb,tap) tile
#define W3_BYTES (40 * W3TILE)         // 819200

#define XROWB 80                       // LDS X row: 32 ci' bf16 (64B) + 16B pad
#define XROWS 264                      // w0-4 .. w0+259 (halo baked in)
#define XBUF (XROWS * XROWB)           // 21120 B

// ---------------- pre-kernel: W fp32 -> bf16, [cb,t][co][ci'] 80B rows ----------------

__global__ void wprep(const float* __restrict__ wgt, u16* __restrict__ W3) {
    int i = blockIdx.x * 256 + threadIdx.x;       // co*1280 + ci*5 + k
    if (i >= NCO * NCI * NK) return;
    int k  = i % NK;
    int ci = (i / NK) % NCI;
    int co = i / (NCI * NK);
    int cb = ci >> 5, cr = ci & 31;
    __hip_bfloat16 h = __float2bfloat16(wgt[i]);
    W3[((size_t)(cb * NK + k) * 256 + co) * 40 + cr] = *reinterpret_cast<u16*>(&h);
}

__device__ __forceinline__ u16 bf16bits(float f) {
    __hip_bfloat16 h = __float2bfloat16(f);
    return *reinterpret_cast<u16*>(&h);
}

// ---------------- fused conv ----------------
// grid 512 = 16 w-tiles x 32 batch; block 512 thr = 8 waves.
// block tile 256co x 256w; wave tile 128co x 64w (wm=wave>>2, wn=wave&3);
// mfma_f32_16x16x32_bf16, acc[8][4] floatx4 = 128 floats (NO spill).
// af from global W3 (L1/L2-hot); bf from LDS X (dbuf, T14, 1 barrier/cb).

__global__ __launch_bounds__(512, 2)
void conv_mfma(const float* __restrict__ x, const u16* __restrict__ W3,
               const float* __restrict__ bias, float* __restrict__ out) {
    __shared__ __align__(16) char xlds[2 * XBUF];   // 42240 B

    const int bid  = blockIdx.x;
    const int wt   = bid & 15;
    const int b    = bid >> 4;
    const int tid  = threadIdx.x;
    const int lane = tid & 63;
    const int wave = tid >> 6;
    const int wm   = wave >> 2;        // co strip: wm*128
    const int wn   = wave & 3;         // w strip:  wn*64
    const int mrow = lane & 15;
    const int g    = lane >> 4;        // 0..3
    const int w0   = wt * 256;

    floatx4 acc[8][4];
#pragma unroll
    for (int mi = 0; mi < 8; ++mi)
#pragma unroll
        for (int ni = 0; ni < 4; ++ni)
            acc[mi][ni] = (floatx4){0.f, 0.f, 0.f, 0.f};

    const float* xb = x + (size_t)b * NCI * NW;

    // main-stage mapping: h = tid>>8 (0/1), wi = tid&255; it 0..7 -> ci0 = it*4 + h*2
    const int h  = tid >> 8;
    const int wi = tid & 255;

    // halo task (threads 0..63): side 0 -> rows 0..3 (w0-4..w0-1), side 1 -> rows 260..263
    const int hside = tid >> 5;
    const int hr    = (tid >> 3) & 3;
    const int hcq   = tid & 7;
    const int hrow  = hside ? (260 + hr) : hr;
    const int hwg   = hside ? (w0 + 256 + hr) : (w0 - 4 + hr);
    const bool hvalid = (hwg >= 0) && (hwg < NW);

    // ---------- prologue: stage cb = 0 into buf 0 ----------
    {
        float va[8], vb[8];
        float hv[4] = {0.f, 0.f, 0.f, 0.f};
#pragma unroll
        for (int it = 0; it < 8; ++it) {
            int ci0 = it * 4 + h * 2;
            va[it] = xb[(size_t)ci0 * NW + w0 + wi];
            vb[it] = xb[(size_t)(ci0 + 1) * NW + w0 + wi];
        }
        if (tid < 64 && hvalid)
#pragma unroll
            for (int q = 0; q < 4; ++q)
                hv[q] = xb[(size_t)(hcq * 4 + q) * NW + hwg];

#pragma unroll
        for (int it = 0; it < 8; ++it) {
            u32 p = (u32)bf16bits(va[it]) | ((u32)bf16bits(vb[it]) << 16);
            *(u32*)(xlds + (wi + 4) * XROWB + (it * 4 + h * 2) * 2) = p;
        }
        if (tid < 64) {
            u64 p = (u64)bf16bits(hv[0]) | ((u64)bf16bits(hv[1]) << 16) |
                    ((u64)bf16bits(hv[2]) << 32) | ((u64)bf16bits(hv[3]) << 48);
            *(u64*)(xlds + hrow * XROWB + hcq * 8) = p;
        }
    }
    __syncthreads();

    // ---------- main loop over 8 ci-blocks ----------
    for (int cb = 0; cb < 8; ++cb) {
        const char* cur = xlds + (cb & 1) * XBUF;
        char* nxt       = xlds + ((cb + 1) & 1) * XBUF;
        const bool more = (cb < 7);

        // T14 issue-early: global loads for cb+1
        float va[8], vb[8];
        float hv[4] = {0.f, 0.f, 0.f, 0.f};
        if (more) {
            const float* xcb = xb + (size_t)((cb + 1) * 32) * NW;
#pragma unroll
            for (int it = 0; it < 8; ++it) {
                int ci0 = it * 4 + h * 2;
                va[it] = xcb[(size_t)ci0 * NW + w0 + wi];
                vb[it] = xcb[(size_t)(ci0 + 1) * NW + w0 + wi];
            }
            if (tid < 64 && hvalid)
#pragma unroll
                for (int q = 0; q < 4; ++q)
                    hv[q] = xcb[(size_t)(hcq * 4 + q) * NW + hwg];
        }

        // compute cb: 5 taps x (8 af-global + 4 bf-LDS + 32 MFMA)
#pragma unroll
        for (int t = 0; t < NK; ++t) {
            const char* wtile = (const char*)W3 + (size_t)(cb * NK + t) * W3TILE;
            short8 af[8], bf[4];
#pragma unroll
            for (int mi = 0; mi < 8; ++mi)
                af[mi] = *(const short8*)(wtile +
                         (wm * 128 + mi * 16 + mrow) * W3ROWB + g * 16);
#pragma unroll
            for (int ni = 0; ni < 4; ++ni)
                bf[ni] = *(const short8*)(cur +
                         (wn * 64 + ni * 16 + mrow + t + 2) * XROWB + g * 16);

            __builtin_amdgcn_s_setprio(1);
#pragma unroll
            for (int mi = 0; mi < 8; ++mi)
#pragma unroll
                for (int ni = 0; ni < 4; ++ni)
                    acc[mi][ni] = __builtin_amdgcn_mfma_f32_16x16x32_bf16(
                        af[mi], bf[ni], acc[mi][ni], 0, 0, 0);
            __builtin_amdgcn_s_setprio(0);
        }

        // T14 write-late: pack + ds_write into the other buffer, then barrier
        if (more) {
#pragma unroll
            for (int it = 0; it < 8; ++it) {
                u32 p = (u32)bf16bits(va[it]) | ((u32)bf16bits(vb[it]) << 16);
                *(u32*)(nxt + (wi + 4) * XROWB + (it * 4 + h * 2) * 2) = p;
            }
            if (tid < 64) {
                u64 p = (u64)bf16bits(hv[0]) | ((u64)bf16bits(hv[1]) << 16) |
                        ((u64)bf16bits(hv[2]) << 32) | ((u64)bf16bits(hv[3]) << 48);
                *(u64*)(nxt + hrow * XROWB + hcq * 8) = p;
            }
            __syncthreads();
        }
    }

    // ---------- epilogue: C/D col=lane&15 (w), row=g*4+r (co) ----------
#pragma unroll
    for (int mi = 0; mi < 8; ++mi) {
        int cobase = wm * 128 + mi * 16 + g * 4;
        float bv[4];
#pragma unroll
        for (int r = 0; r < 4; ++r) bv[r] = bias[cobase + r];
#pragma unroll
        for (int ni = 0; ni < 4; ++ni) {
            int col = w0 + wn * 64 + ni * 16 + mrow;
#pragma unroll
            for (int r = 0; r < 4; ++r)
                out[((size_t)b * NCO + cobase + r) * NW + col] =
                    acc[mi][ni][r] + bv[r];
        }
    }
}

// ---------------- fallback (ws too small): naive fp32 ----------------

__global__ void conv_naive(const float* __restrict__ x, const float* __restrict__ wgt,
                           const float* __restrict__ bias, float* __restrict__ out) {
    int w  = blockIdx.x * 256 + threadIdx.x;
    int co = blockIdx.y;
    int b  = blockIdx.z;
    float acc = bias[co];
    for (int ci = 0; ci < NCI; ci++) {
        const float* xr = x + ((size_t)b * NCI + ci) * NW;
        const float* wr = wgt + ((size_t)co * NCI + ci) * NK;
#pragma unroll
        for (int k = 0; k < NK; k++) {
            int wi = w + k - 2;
            if (wi >= 0 && wi < NW) acc += xr[wi] * wr[k];
        }
    }
    out[((size_t)b * NCO + co) * NW + w] = acc;
}

// ---------------- launch ----------------

extern "C" void kernel_launch(void* const* d_in, const int* in_sizes, int n_in,
                              void* d_out, int out_size, void* d_ws, size_t ws_size,
                              hipStream_t stream) {
    const float* x    = (const float*)d_in[0];
    const float* wgt  = (const float*)d_in[1];
    const float* bias = (const float*)d_in[2];
    float* out        = (float*)d_out;

    if (ws_size < (size_t)W3_BYTES) {
        conv_naive<<<dim3(NW / 256, NCO, NB), 256, 0, stream>>>(x, wgt, bias, out);
        return;
    }

    u16* W3 = (u16*)d_ws;
    wprep<<<(NCO * NCI * NK + 255) / 256, 256, 0, stream>>>(wgt, W3);
    conv_mfma<<<512, 512, 0, stream>>>(x, W3, bias, out);
}